// Round 16
// baseline (165.330 us; speedup 1.0000x reference)
//
#include <hip/hip_runtime.h>
#include <hip/hip_bf16.h>

typedef __attribute__((ext_vector_type(8))) short short8;
typedef float floatx4 __attribute__((ext_vector_type(4)));
typedef float floatx16 __attribute__((ext_vector_type(16)));

#define LQ 4096
#define LK 1024
#define NH 24
#define HD 128
#define HID 3072

__device__ __forceinline__ unsigned short f2bf(float f) {
    __hip_bfloat16 h = __float2bfloat16(f);
    union { __hip_bfloat16 b; unsigned short u; } c; c.b = h;
    return c.u;
}

// pack two f32 -> packed 2x bf16 in one instr (RNE)
__device__ __forceinline__ unsigned cvtpk(float a, float b) {
    unsigned r;
    asm("v_cvt_pk_bf16_f32 %0, %1, %2" : "=v"(r) : "v"(a), "v"(b));
    return r;
}

// guaranteed single-instruction 2^x
__device__ __forceinline__ float fexp2(float x) {
    float r;
    asm("v_exp_f32 %0, %1" : "=v"(r) : "v"(x));
    return r;
}

// async global->LDS, 16B per lane. LDS dest must be wave-uniform base (HW adds lane*16).
__device__ __forceinline__ void gload16(const void* g, void* l) {
    __builtin_amdgcn_global_load_lds(
        (const __attribute__((address_space(1))) void*)g,
        (__attribute__((address_space(3))) void*)l,
        16, 0, 0);
}

// ---------------- f32 -> bf16 convert ----------------
__global__ void f32_to_bf16(const float* __restrict__ in, unsigned short* __restrict__ out, int n4) {
    int i = blockIdx.x * blockDim.x + threadIdx.x;
    int stride = gridDim.x * blockDim.x;
    for (; i < n4; i += stride) {
        float4 v = ((const float4*)in)[i];
        ushort4 o;
        o.x = f2bf(v.x); o.y = f2bf(v.y); o.z = f2bf(v.z); o.w = f2bf(v.w);
        ((ushort4*)out)[i] = o;
    }
}

// ---------------- bf16 GEMM, split-K=2 (proven round-8 structure) ----------------
__global__ __launch_bounds__(256) void gemm_proj(const unsigned short* __restrict__ A,
                                                 const unsigned short* __restrict__ Bw,
                                                 float* __restrict__ C,
                                                 int M, int N, int K) {
    __shared__ __align__(16) unsigned short As[2][64 * 64];
    __shared__ __align__(16) unsigned short Bs[2][128 * 64];
    const int tid = threadIdx.x;
    const int lane = tid & 63;
    const int wave = tid >> 6;
    const int wm = wave >> 1, wn = wave & 1;
    const int flat = blockIdx.x + gridDim.x * blockIdx.y;  // 0..383 within z-slice
    const int wid = (flat & 7) * 48 + (flat >> 3);         // XCD-contiguous
    const int bm0 = (wid & 15) * 64;
    const int bn0 = (wid >> 4) * 128;
    const int kbeg = blockIdx.z * (K >> 1);
    const int kend = kbeg + (K >> 1);
    float* Cz = C + (size_t)blockIdx.z * M * N;
    const int lr = lane & 15;
    const int lg = lane >> 4;

    floatx4 acc[2][4];
    for (int i = 0; i < 2; ++i)
        for (int j = 0; j < 4; ++j)
            acc[i][j] = (floatx4){0.f, 0.f, 0.f, 0.f};

    auto stage = [&](int b, int k0) {
        for (int p = 0; p < 2; ++p) {
            int slot = p * 256 + tid;
            int r = slot >> 3, cb = slot & 7;
            int g = cb ^ (r & 7);
            gload16(&A[(bm0 + r) * K + k0 + g * 8], &As[b][(p * 256 + wave * 64) * 8]);
        }
        for (int p = 0; p < 4; ++p) {
            int slot = p * 256 + tid;
            int r = slot >> 3, cb = slot & 7;
            int g = cb ^ (r & 7);
            gload16(&Bw[(bn0 + r) * K + k0 + g * 8], &Bs[b][(p * 256 + wave * 64) * 8]);
        }
    };

    auto compute = [&](int b) {
        for (int ks = 0; ks < 2; ++ks) {
            short8 af[2], bfr[4];
            for (int mt = 0; mt < 2; ++mt) {
                int m = wm * 32 + mt * 16 + lr;
                int sc = (ks * 4 + lg) ^ (m & 7);
                af[mt] = *(const short8*)(&As[b][m * 64 + sc * 8]);
            }
            for (int nt = 0; nt < 4; ++nt) {
                int n = wn * 64 + nt * 16 + lr;
                int sc = (ks * 4 + lg) ^ (n & 7);
                bfr[nt] = *(const short8*)(&Bs[b][n * 64 + sc * 8]);
            }
            __builtin_amdgcn_s_setprio(1);
            for (int mt = 0; mt < 2; ++mt)
                for (int nt = 0; nt < 4; ++nt)
                    acc[mt][nt] = __builtin_amdgcn_mfma_f32_16x16x32_bf16(af[mt], bfr[nt], acc[mt][nt], 0, 0, 0);
            __builtin_amdgcn_s_setprio(0);
        }
    };

    stage(0, kbeg);
    __syncthreads();
    int buf = 0;
    for (int k0 = kbeg; k0 < kend - 64; k0 += 64) {
        stage(buf ^ 1, k0 + 64);
        compute(buf);
        __syncthreads();
        buf ^= 1;
    }
    compute(buf);

    for (int mt = 0; mt < 2; ++mt)
        for (int nt = 0; nt < 4; ++nt)
            for (int rg = 0; rg < 4; ++rg) {
                int m = bm0 + wm * 32 + mt * 16 + lg * 4 + rg;
                int n = bn0 + wn * 64 + nt * 16 + lr;
                Cz[m * N + n] = acc[mt][nt][rg];
            }
}

// ---------------- RMSNorm + RoPE on K (reads two split-K partials) ----------------
__global__ __launch_bounds__(256) void rmsnorm_rope(const float* __restrict__ r0,
                                                    const float* __restrict__ r1,
                                                    const float* __restrict__ freqs,
                                                    const float* __restrict__ w,
                                                    unsigned short* __restrict__ Kbf) {
    int row = blockIdx.x * 2 + (threadIdx.x >> 7);  // l*NH + h
    int l = row / NH, h = row % NH;
    int d = threadIdx.x & 127;
    int idx = l * HID + h * HD + d;
    float x = r0[idx] + r1[idx];
    float ss = x * x;
    for (int off = 32; off; off >>= 1) ss += __shfl_xor(ss, off);
    __shared__ float red[4];
    int wv = threadIdx.x >> 6;
    if ((threadIdx.x & 63) == 0) red[wv] = ss;
    __syncthreads();
    int base = (threadIdx.x >> 7) * 2;
    float tot = red[base] + red[base + 1];
    float rsn = rsqrtf(tot * (1.0f / 128.0f) + 1e-6f);
    float xn = x * rsn * w[d];
    float f = freqs[l * (HD / 2) + (d >> 1)];
    float s = __sinf(f), c = __cosf(f);   // freqs in [0,1): no range reduction needed
    float partner = __shfl_xor(xn, 1);
    float o = (d & 1) ? (partner * s + xn * c) : (xn * c - partner * s);
    Kbf[idx] = f2bf(o);
}

// ---------------- V transpose -> FRAGMENT-ORDER global layout (32-key tiles) ----
// Vfrag[h][kt32][ntd][c][hi][l31]: 16B vector = bf16 V[kt32*32 + c*16 + hi*8 + j]
// [hd = h*128 + ntd*32 + l31]. One head+ktile = contiguous 8KB -> attn stages it
// with 2 linear gload16; reads hit 32 consecutive slots (conflict-free).
__global__ __launch_bounds__(256) void transpose_v(const float* __restrict__ r0,
                                                   const float* __restrict__ r1,
                                                   unsigned short* __restrict__ Vfrag) {
    __shared__ float tile[32][65];
    const int bx = blockIdx.x;          // hd0/64: 0..47
    const int by = blockIdx.y;          // kt32: 0..31
    const int hd0 = bx * 64, l0 = by * 32;
    const int tx = threadIdx.x & 63;
    const int tg8 = threadIdx.x >> 6;   // 0..3
    for (int i = 0; i < 8; ++i) {
        int r = tg8 * 8 + i;
        int idx = (l0 + r) * HID + hd0 + tx;
        tile[r][tx] = r0[idx] + r1[idx];
    }
    __syncthreads();
    const int tg = threadIdx.x >> 6;    // 0..3
    const int c = tg >> 1, hi = tg & 1;
    const int hdl = threadIdx.x & 63;
    const int kloc = c * 16 + hi * 8;
    short8 v;
    for (int j = 0; j < 8; ++j)
        v[j] = (short)f2bf(tile[kloc + j][hdl]);
    const int hd = hd0 + hdl;
    const int h = hd >> 7;
    const int ntd = (hd & 127) >> 5;
    const int l31 = hd & 31;
    size_t pos = ((((size_t)(h * 32 + by) * 4 + ntd) * 2 + c) * 2 + hi) * 32 + l31;
    *(short8*)(&Vfrag[pos * 8]) = v;
}

// ---------------- Flash attention (round-15 + triple-buffer counted vmcnt) ------
// KVBLK=32; K and V TRIPLE-buffered (48KB LDS, 3 blocks/CU). Per iter:
// stage(t+2) -> compute(t) -> s_waitcnt vmcnt(4) -> s_barrier. Tile t+1's 4 loads
// retired; tile t+2's 4 loads stay in flight ACROSS the barrier (T4: never drain
// vmcnt to 0 in the main loop). Safety: write target (t+2)%3 != read target t%3;
// every buffer's loads vmcnt-retired by every wave before the barrier preceding
// its first read (round-11 rule); gload16 only touches vmcnt, compute's ds_read
// results consumed before barrier -> raw s_barrier is sufficient.
// Compute body = round-15 verified: split-accumulator QK (2x4 dependent MFMAs),
// raw v_exp_f32, tree psum, cvt_pk + permlane32_swap, fragment-order V, setprio.
__global__ __launch_bounds__(256, 3) void attn(const float* __restrict__ Q,
                                               const unsigned short* __restrict__ Kbf,
                                               const unsigned short* __restrict__ Vfrag,
                                               float* __restrict__ O) {
    __shared__ __align__(16) unsigned short Ks[3][32 * 128];   // [key][d], src-swizzled
    __shared__ __align__(16) unsigned short Vs[3][32 * 128];   // fragment-order, linear
    const int tid = threadIdx.x;
    const int lane = tid & 63;
    const int wave = tid >> 6;
    const int l31 = lane & 31;
    const int hi = lane >> 5;
    const int flat = blockIdx.x + gridDim.x * blockIdx.y;  // gridDim.x = 32
    const int wid = (flat & 7) * 96 + (flat >> 3);          // bijective: 768 = 8*96
    const int h = wid >> 5;
    const int q0 = (wid & 31) * 128 + wave * 32;
    const float qscale = 0.08838834764831843f * 1.44269504088896340736f;  // D^-0.5 * log2(e)
    const float SHIFT = 32.0f;
    const int NT = LK / 32;  // 32 kv-tiles

    // hoist Q B-fragments: lane holds Q[q0+l31][m*16 + hi*8 + j], m=0..7
    short8 qf[8];
#pragma unroll
    for (int m = 0; m < 8; ++m) {
        const float* qp = &Q[(q0 + l31) * HID + h * HD + m * 16 + hi * 8];
        float4 lo = *(const float4*)(qp);
        float4 hif = *(const float4*)(qp + 4);
        short8 v;
        v[0] = (short)f2bf(lo.x * qscale);
        v[1] = (short)f2bf(lo.y * qscale);
        v[2] = (short)f2bf(lo.z * qscale);
        v[3] = (short)f2bf(lo.w * qscale);
        v[4] = (short)f2bf(hif.x * qscale);
        v[5] = (short)f2bf(hif.y * qscale);
        v[6] = (short)f2bf(hif.z * qscale);
        v[7] = (short)f2bf(hif.w * qscale);
        qf[m] = v;
    }

    floatx16 accO[4];
#pragma unroll
    for (int i = 0; i < 4; ++i)
#pragma unroll
        for (int r = 0; r < 16; ++r) accO[i][r] = 0.f;
    float psum = 0.f;

    auto stageK = [&](int b, int kt) {
        for (int i = 0; i < 2; ++i) {
            int slot = i * 256 + tid;             // 512 slots = 32 rows x 16 blocks
            int r = slot >> 4, bb = slot & 15;
            int g = bb ^ (r & 15);
            gload16(&Kbf[(kt * 32 + r) * HID + h * HD + g * 8],
                    &Ks[b][(i * 256 + wave * 64) * 8]);
        }
    };
    auto stageV = [&](int b, int kt) {
        const unsigned short* src = Vfrag + ((size_t)(h * 32 + kt) << 12);  // 8KB tile
        for (int i = 0; i < 2; ++i) {
            int slot = i * 256 + tid;
            gload16(&src[slot * 8], &Vs[b][(i * 256 + wave * 64) * 8]);
        }
    };

    auto compute = [&](int b) {
        floatx16 sa, sb;
#pragma unroll
        for (int r = 0; r < 16; ++r) { sa[r] = -SHIFT; sb[r] = 0.f; }
        // QK^T, split accumulators: two independent chains of 4 dependent MFMAs
        __builtin_amdgcn_s_setprio(1);
#pragma unroll
        for (int m = 0; m < 4; ++m) {
            int ca = m * 2 + hi;
            int cb2 = (m + 4) * 2 + hi;
            int slota = l31 * 16 + (ca ^ (l31 & 15));
            int slotb = l31 * 16 + (cb2 ^ (l31 & 15));
            short8 kfa = *(const short8*)(&Ks[b][slota * 8]);
            short8 kfb = *(const short8*)(&Ks[b][slotb * 8]);
            sa = __builtin_amdgcn_mfma_f32_32x32x16_bf16(kfa, qf[m], sa, 0, 0, 0);
            sb = __builtin_amdgcn_mfma_f32_32x32x16_bf16(kfb, qf[m + 4], sb, 0, 0, 0);
        }
        __builtin_amdgcn_s_setprio(0);
        // softmax: e = exp2(sa+sb); cvt_pk pack; permlane32_swap -> A-fragments
        float e[16];
#pragma unroll
        for (int r = 0; r < 16; ++r) e[r] = fexp2(sa[r] + sb[r]);
        // tree psum (no fast-math: explicit reassociation)
        {
            float s01 = e[0] + e[1],   s23 = e[2] + e[3];
            float s45 = e[4] + e[5],   s67 = e[6] + e[7];
            float s89 = e[8] + e[9],   sab = e[10] + e[11];
            float scd = e[12] + e[13], sef = e[14] + e[15];
            float t0 = s01 + s23, t1 = s45 + s67, t2 = s89 + sab, t3 = scd + sef;
            psum += (t0 + t1) + (t2 + t3);
        }
        unsigned d0 = cvtpk(e[0], e[1]),   d1 = cvtpk(e[2], e[3]);
        unsigned d2 = cvtpk(e[4], e[5]),   d3 = cvtpk(e[6], e[7]);
        unsigned d4 = cvtpk(e[8], e[9]),   d5 = cvtpk(e[10], e[11]);
        unsigned d6 = cvtpk(e[12], e[13]), d7 = cvtpk(e[14], e[15]);
        asm volatile("v_permlane32_swap_b32 %0, %1" : "+v"(d0), "+v"(d2));
        asm volatile("v_permlane32_swap_b32 %0, %1" : "+v"(d1), "+v"(d3));
        asm volatile("v_permlane32_swap_b32 %0, %1" : "+v"(d4), "+v"(d6));
        asm volatile("v_permlane32_swap_b32 %0, %1" : "+v"(d5), "+v"(d7));
        union { unsigned u[4]; short8 s; } p0, p1;
        p0.u[0] = d0; p0.u[1] = d1; p0.u[2] = d2; p0.u[3] = d3;  // keys 0..15
        p1.u[0] = d4; p1.u[1] = d5; p1.u[2] = d6; p1.u[3] = d7;  // keys 16..31
        // O += P V: B-fragment slot = ((ntd*2 + c)*2 + hi)*32 + l31 — conflict-free
        __builtin_amdgcn_s_setprio(1);
#pragma unroll
        for (int ntd = 0; ntd < 4; ++ntd) {
            int s0 = ((ntd * 2 + 0) * 2 + hi) * 32 + l31;
            int s1 = ((ntd * 2 + 1) * 2 + hi) * 32 + l31;
            short8 vf0 = *(const short8*)(&Vs[b][s0 * 8]);
            short8 vf1 = *(const short8*)(&Vs[b][s1 * 8]);
            accO[ntd] = __builtin_amdgcn_mfma_f32_32x32x16_bf16(p0.s, vf0, accO[ntd], 0, 0, 0);
            accO[ntd] = __builtin_amdgcn_mfma_f32_32x32x16_bf16(p1.s, vf1, accO[ntd], 0, 0, 0);
        }
        __builtin_amdgcn_s_setprio(0);
    };

    // prologue: tiles 0 and 1 issued; retire tile 0 (vmcnt(4)), keep tile 1 flying
    stageK(0, 0); stageV(0, 0);
    stageK(1, 1); stageV(1, 1);
    asm volatile("s_waitcnt vmcnt(4)" ::: "memory");
    __builtin_amdgcn_s_barrier();

    for (int t = 0; t < NT; ++t) {
        if (t + 2 < NT) {
            int nb = (t + 2) % 3;          // != t%3 (read) and != (t+1)%3 (in flight)
            stageK(nb, t + 2);
            stageV(nb, t + 2);
            compute(t % 3);
            asm volatile("s_waitcnt vmcnt(4)" ::: "memory");  // t+1 retired, t+2 flying
            __builtin_amdgcn_s_barrier();
        } else if (t + 1 < NT) {
            compute(t % 3);
            asm volatile("s_waitcnt vmcnt(0)" ::: "memory");  // final drain
            __builtin_amdgcn_s_barrier();
        } else {
            compute(t % 3);
        }
    }

    // epilogue: psum covers half the keys; partner (lane^32) has the rest
    float s = psum + __shfl_xor(psum, 32);
    float rinv = 1.0f / s;  // valid for q = l31
    float ri[16];
#pragma unroll
    for (int r = 0; r < 16; ++r) {
        int row = (r & 3) + 8 * (r >> 2) + 4 * hi;
        ri[r] = __shfl(rinv, row);
    }
#pragma unroll
    for (int ntd = 0; ntd < 4; ++ntd)
#pragma unroll
        for (int r = 0; r < 16; ++r) {
            int row = (r & 3) + 8 * (r >> 2) + 4 * hi;
            O[(q0 + row) * HID + h * HD + ntd * 32 + l31] = accO[ntd][r] * ri[r];
        }
}

extern "C" void kernel_launch(void* const* d_in, const int* in_sizes, int n_in,
                              void* d_out, int out_size, void* d_ws, size_t ws_size,
                              hipStream_t stream) {
    const float* Q      = (const float*)d_in[0];
    const float* latent = (const float*)d_in[1];
    const float* freqs  = (const float*)d_in[2];
    const float* Wk     = (const float*)d_in[3];
    const float* Wv     = (const float*)d_in[4];
    const float* rmsw   = (const float*)d_in[5];
    float* out = (float*)d_out;
    char* ws = (char*)d_ws;

    // ws layout (62,914,560 bytes; Wv reuses Wk's slot — stream order serializes)
    unsigned short* latent_bf = (unsigned short*)(ws);               //  6,291,456
    unsigned short* Wbf       = (unsigned short*)(ws + 6291456);     // 18,874,368 (Wk, then Wv)
    float*          raw0      = (float*)(ws + 25165824);             // 12,582,912 split-K partial 0
    float*          raw1      = (float*)(ws + 37748736);             // 12,582,912 split-K partial 1
    unsigned short* Kbf       = (unsigned short*)(ws + 50331648);    //  6,291,456
    unsigned short* Vfrag     = (unsigned short*)(ws + 56623104);    //  6,291,456

    f32_to_bf16<<<2048, 256, 0, stream>>>(latent, latent_bf, (LK * HID) / 4);
    f32_to_bf16<<<2048, 256, 0, stream>>>(Wk, Wbf, (HID * HID) / 4);

    gemm_proj<<<dim3(16, 24, 2), 256, 0, stream>>>(latent_bf, Wbf, raw0, LK, HID, HID);
    rmsnorm_rope<<<(LK * NH) / 2, 256, 0, stream>>>(raw0, raw1, freqs, rmsw, Kbf);

    f32_to_bf16<<<2048, 256, 0, stream>>>(Wv, Wbf, (HID * HID) / 4);
    gemm_proj<<<dim3(16, 24, 2), 256, 0, stream>>>(latent_bf, Wbf, raw0, LK, HID, HID);
    transpose_v<<<dim3(HID / 64, LK / 32), 256, 0, stream>>>(raw0, raw1, Vfrag);

    attn<<<dim3(LQ / 128, NH), 256, 0, stream>>>(Q, Kbf, Vfrag, out);
}

// Round 17
// 161.619 us; speedup vs baseline: 1.0230x; 1.0230x over previous
//
#include <hip/hip_runtime.h>
#include <hip/hip_bf16.h>

typedef __attribute__((ext_vector_type(8))) short short8;
typedef float floatx4 __attribute__((ext_vector_type(4)));
typedef float floatx16 __attribute__((ext_vector_type(16)));

#define LQ 4096
#define LK 1024
#define NH 24
#define HD 128
#define HID 3072

__device__ __forceinline__ unsigned short f2bf(float f) {
    __hip_bfloat16 h = __float2bfloat16(f);
    union { __hip_bfloat16 b; unsigned short u; } c; c.b = h;
    return c.u;
}

// pack two f32 -> packed 2x bf16 in one instr (RNE)
__device__ __forceinline__ unsigned cvtpk(float a, float b) {
    unsigned r;
    asm("v_cvt_pk_bf16_f32 %0, %1, %2" : "=v"(r) : "v"(a), "v"(b));
    return r;
}

// guaranteed single-instruction 2^x
__device__ __forceinline__ float fexp2(float x) {
    float r;
    asm("v_exp_f32 %0, %1" : "=v"(r) : "v"(x));
    return r;
}

// async global->LDS, 16B per lane. LDS dest must be wave-uniform base (HW adds lane*16).
__device__ __forceinline__ void gload16(const void* g, void* l) {
    __builtin_amdgcn_global_load_lds(
        (const __attribute__((address_space(1))) void*)g,
        (__attribute__((address_space(3))) void*)l,
        16, 0, 0);
}

// ---------------- f32 -> bf16 convert ----------------
__global__ void f32_to_bf16(const float* __restrict__ in, unsigned short* __restrict__ out, int n4) {
    int i = blockIdx.x * blockDim.x + threadIdx.x;
    int stride = gridDim.x * blockDim.x;
    for (; i < n4; i += stride) {
        float4 v = ((const float4*)in)[i];
        ushort4 o;
        o.x = f2bf(v.x); o.y = f2bf(v.y); o.z = f2bf(v.z); o.w = f2bf(v.w);
        ((ushort4*)out)[i] = o;
    }
}

// ---------------- bf16 GEMM, split-K=2 (proven round-8 structure) ----------------
__global__ __launch_bounds__(256) void gemm_proj(const unsigned short* __restrict__ A,
                                                 const unsigned short* __restrict__ Bw,
                                                 float* __restrict__ C,
                                                 int M, int N, int K) {
    __shared__ __align__(16) unsigned short As[2][64 * 64];
    __shared__ __align__(16) unsigned short Bs[2][128 * 64];
    const int tid = threadIdx.x;
    const int lane = tid & 63;
    const int wave = tid >> 6;
    const int wm = wave >> 1, wn = wave & 1;
    const int flat = blockIdx.x + gridDim.x * blockIdx.y;  // 0..383 within z-slice
    const int wid = (flat & 7) * 48 + (flat >> 3);         // XCD-contiguous
    const int bm0 = (wid & 15) * 64;
    const int bn0 = (wid >> 4) * 128;
    const int kbeg = blockIdx.z * (K >> 1);
    const int kend = kbeg + (K >> 1);
    float* Cz = C + (size_t)blockIdx.z * M * N;
    const int lr = lane & 15;
    const int lg = lane >> 4;

    floatx4 acc[2][4];
    for (int i = 0; i < 2; ++i)
        for (int j = 0; j < 4; ++j)
            acc[i][j] = (floatx4){0.f, 0.f, 0.f, 0.f};

    auto stage = [&](int b, int k0) {
        for (int p = 0; p < 2; ++p) {
            int slot = p * 256 + tid;
            int r = slot >> 3, cb = slot & 7;
            int g = cb ^ (r & 7);
            gload16(&A[(bm0 + r) * K + k0 + g * 8], &As[b][(p * 256 + wave * 64) * 8]);
        }
        for (int p = 0; p < 4; ++p) {
            int slot = p * 256 + tid;
            int r = slot >> 3, cb = slot & 7;
            int g = cb ^ (r & 7);
            gload16(&Bw[(bn0 + r) * K + k0 + g * 8], &Bs[b][(p * 256 + wave * 64) * 8]);
        }
    };

    auto compute = [&](int b) {
        for (int ks = 0; ks < 2; ++ks) {
            short8 af[2], bfr[4];
            for (int mt = 0; mt < 2; ++mt) {
                int m = wm * 32 + mt * 16 + lr;
                int sc = (ks * 4 + lg) ^ (m & 7);
                af[mt] = *(const short8*)(&As[b][m * 64 + sc * 8]);
            }
            for (int nt = 0; nt < 4; ++nt) {
                int n = wn * 64 + nt * 16 + lr;
                int sc = (ks * 4 + lg) ^ (n & 7);
                bfr[nt] = *(const short8*)(&Bs[b][n * 64 + sc * 8]);
            }
            __builtin_amdgcn_s_setprio(1);
            for (int mt = 0; mt < 2; ++mt)
                for (int nt = 0; nt < 4; ++nt)
                    acc[mt][nt] = __builtin_amdgcn_mfma_f32_16x16x32_bf16(af[mt], bfr[nt], acc[mt][nt], 0, 0, 0);
            __builtin_amdgcn_s_setprio(0);
        }
    };

    stage(0, kbeg);
    __syncthreads();
    int buf = 0;
    for (int k0 = kbeg; k0 < kend - 64; k0 += 64) {
        stage(buf ^ 1, k0 + 64);
        compute(buf);
        __syncthreads();
        buf ^= 1;
    }
    compute(buf);

    for (int mt = 0; mt < 2; ++mt)
        for (int nt = 0; nt < 4; ++nt)
            for (int rg = 0; rg < 4; ++rg) {
                int m = bm0 + wm * 32 + mt * 16 + lg * 4 + rg;
                int n = bn0 + wn * 64 + nt * 16 + lr;
                Cz[m * N + n] = acc[mt][nt][rg];
            }
}

// ---------------- RMSNorm + RoPE on K (reads two split-K partials) ----------------
__global__ __launch_bounds__(256) void rmsnorm_rope(const float* __restrict__ r0,
                                                    const float* __restrict__ r1,
                                                    const float* __restrict__ freqs,
                                                    const float* __restrict__ w,
                                                    unsigned short* __restrict__ Kbf) {
    int row = blockIdx.x * 2 + (threadIdx.x >> 7);  // l*NH + h
    int l = row / NH, h = row % NH;
    int d = threadIdx.x & 127;
    int idx = l * HID + h * HD + d;
    float x = r0[idx] + r1[idx];
    float ss = x * x;
    for (int off = 32; off; off >>= 1) ss += __shfl_xor(ss, off);
    __shared__ float red[4];
    int wv = threadIdx.x >> 6;
    if ((threadIdx.x & 63) == 0) red[wv] = ss;
    __syncthreads();
    int base = (threadIdx.x >> 7) * 2;
    float tot = red[base] + red[base + 1];
    float rsn = rsqrtf(tot * (1.0f / 128.0f) + 1e-6f);
    float xn = x * rsn * w[d];
    float f = freqs[l * (HD / 2) + (d >> 1)];
    float s = __sinf(f), c = __cosf(f);   // freqs in [0,1): no range reduction needed
    float partner = __shfl_xor(xn, 1);
    float o = (d & 1) ? (partner * s + xn * c) : (xn * c - partner * s);
    Kbf[idx] = f2bf(o);
}

// ---------------- V transpose -> FRAGMENT-ORDER global layout (32-key tiles) ----
// Vfrag[h][kt32][ntd][c][hi][l31]: 16B vector = bf16 V[kt32*32 + c*16 + hi*8 + j]
// [hd = h*128 + ntd*32 + l31]. One head+ktile = contiguous 8KB -> attn stages it
// with 2 linear gload16; reads hit 32 consecutive slots (conflict-free).
__global__ __launch_bounds__(256) void transpose_v(const float* __restrict__ r0,
                                                   const float* __restrict__ r1,
                                                   unsigned short* __restrict__ Vfrag) {
    __shared__ float tile[32][65];
    const int bx = blockIdx.x;          // hd0/64: 0..47
    const int by = blockIdx.y;          // kt32: 0..31
    const int hd0 = bx * 64, l0 = by * 32;
    const int tx = threadIdx.x & 63;
    const int tg8 = threadIdx.x >> 6;   // 0..3
    for (int i = 0; i < 8; ++i) {
        int r = tg8 * 8 + i;
        int idx = (l0 + r) * HID + hd0 + tx;
        tile[r][tx] = r0[idx] + r1[idx];
    }
    __syncthreads();
    const int tg = threadIdx.x >> 6;    // 0..3
    const int c = tg >> 1, hi = tg & 1;
    const int hdl = threadIdx.x & 63;
    const int kloc = c * 16 + hi * 8;
    short8 v;
    for (int j = 0; j < 8; ++j)
        v[j] = (short)f2bf(tile[kloc + j][hdl]);
    const int hd = hd0 + hdl;
    const int h = hd >> 7;
    const int ntd = (hd & 127) >> 5;
    const int l31 = hd & 31;
    size_t pos = ((((size_t)(h * 32 + by) * 4 + ntd) * 2 + c) * 2 + hi) * 32 + l31;
    *(short8*)(&Vfrag[pos * 8]) = v;
}

// ---------------- Flash attention (dual independent kv-streams per wave) --------
// Each wave owns 32 q-rows and TWO independent kv-streams: A = tiles 0..15,
// B = tiles 16..31. Per phase, QK runs two interleaved 8-MFMA chains (sA on KA,
// sB on KB — independent, fills dependency bubbles at fixed 3 waves/SIMD), the
// softmax runs as two sequential 16-exp2 blocks (register-peak control), and PV
// feeds 4 independent accO chains with 4 A-fragments each. Both streams share
// accO/psum (fixed-shift softmax => partials additive) — no combine needed.
// LDS: KA/KB double-buffered (32K) + VA/VB single (16K) = 48KB, 3 blocks/CU.
// V single-buffer safety: stage at phase top -> mid-phase __syncthreads (drain +
// cross-wave visibility) -> PV -> end barrier before next overwrite (r11 rule).
__global__ __launch_bounds__(256, 3) void attn(const float* __restrict__ Q,
                                               const unsigned short* __restrict__ Kbf,
                                               const unsigned short* __restrict__ Vfrag,
                                               float* __restrict__ O) {
    __shared__ __align__(16) unsigned short KA[2][32 * 128];   // stream A K, src-swizzled
    __shared__ __align__(16) unsigned short KB[2][32 * 128];   // stream B K
    __shared__ __align__(16) unsigned short VA[32 * 128];      // stream A V, fragment-order
    __shared__ __align__(16) unsigned short VB[32 * 128];      // stream B V
    const int tid = threadIdx.x;
    const int lane = tid & 63;
    const int wave = tid >> 6;
    const int l31 = lane & 31;
    const int hi = lane >> 5;
    const int flat = blockIdx.x + gridDim.x * blockIdx.y;  // gridDim.x = 32
    const int wid = (flat & 7) * 96 + (flat >> 3);          // bijective: 768 = 8*96
    const int h = wid >> 5;
    const int q0 = (wid & 31) * 128 + wave * 32;
    const float qscale = 0.08838834764831843f * 1.44269504088896340736f;  // D^-0.5 * log2(e)
    const float SHIFT = 32.0f;

    // hoist Q B-fragments: lane holds Q[q0+l31][m*16 + hi*8 + j], m=0..7
    short8 qf[8];
#pragma unroll
    for (int m = 0; m < 8; ++m) {
        const float* qp = &Q[(q0 + l31) * HID + h * HD + m * 16 + hi * 8];
        float4 lo = *(const float4*)(qp);
        float4 hif = *(const float4*)(qp + 4);
        short8 v;
        v[0] = (short)f2bf(lo.x * qscale);
        v[1] = (short)f2bf(lo.y * qscale);
        v[2] = (short)f2bf(lo.z * qscale);
        v[3] = (short)f2bf(lo.w * qscale);
        v[4] = (short)f2bf(hif.x * qscale);
        v[5] = (short)f2bf(hif.y * qscale);
        v[6] = (short)f2bf(hif.z * qscale);
        v[7] = (short)f2bf(hif.w * qscale);
        qf[m] = v;
    }

    floatx16 accO[4];
#pragma unroll
    for (int i = 0; i < 4; ++i)
#pragma unroll
        for (int r = 0; r < 16; ++r) accO[i][r] = 0.f;
    float psum = 0.f;

    auto stageK = [&](unsigned short* dst, int kt) {
        for (int i = 0; i < 2; ++i) {
            int slot = i * 256 + tid;             // 512 slots = 32 rows x 16 blocks
            int r = slot >> 4, bb = slot & 15;
            int g = bb ^ (r & 15);
            gload16(&Kbf[(kt * 32 + r) * HID + h * HD + g * 8],
                    &dst[(i * 256 + wave * 64) * 8]);
        }
    };
    auto stageV = [&](unsigned short* dst, int kt) {
        const unsigned short* src = Vfrag + ((size_t)(h * 32 + kt) << 12);  // 8KB tile
        for (int i = 0; i < 2; ++i) {
            int slot = i * 256 + tid;
            gload16(&src[slot * 8], &dst[(i * 256 + wave * 64) * 8]);
        }
    };

    // softmax for one 32-key S-block -> two PV A-fragments + psum
    auto softmax32 = [&](floatx16 s, short8& pa, short8& pb) {
        float e[16];
#pragma unroll
        for (int r = 0; r < 16; ++r) e[r] = fexp2(s[r]);
        {
            float s01 = e[0] + e[1],   s23 = e[2] + e[3];
            float s45 = e[4] + e[5],   s67 = e[6] + e[7];
            float s89 = e[8] + e[9],   sab = e[10] + e[11];
            float scd = e[12] + e[13], sef = e[14] + e[15];
            float t0 = s01 + s23, t1 = s45 + s67, t2 = s89 + sab, t3 = scd + sef;
            psum += (t0 + t1) + (t2 + t3);
        }
        unsigned d0 = cvtpk(e[0], e[1]),   d1 = cvtpk(e[2], e[3]);
        unsigned d2 = cvtpk(e[4], e[5]),   d3 = cvtpk(e[6], e[7]);
        unsigned d4 = cvtpk(e[8], e[9]),   d5 = cvtpk(e[10], e[11]);
        unsigned d6 = cvtpk(e[12], e[13]), d7 = cvtpk(e[14], e[15]);
        asm volatile("v_permlane32_swap_b32 %0, %1" : "+v"(d0), "+v"(d2));
        asm volatile("v_permlane32_swap_b32 %0, %1" : "+v"(d1), "+v"(d3));
        asm volatile("v_permlane32_swap_b32 %0, %1" : "+v"(d4), "+v"(d6));
        asm volatile("v_permlane32_swap_b32 %0, %1" : "+v"(d5), "+v"(d7));
        union { unsigned u[4]; short8 s; } p0, p1;
        p0.u[0] = d0; p0.u[1] = d1; p0.u[2] = d2; p0.u[3] = d3;  // keys 0..15
        p1.u[0] = d4; p1.u[1] = d5; p1.u[2] = d6; p1.u[3] = d7;  // keys 16..31
        pa = p0.s; pb = p1.s;
    };

    // prologue: first K tiles of both streams
    stageK(KA[0], 0);
    stageK(KB[0], 16);
    asm volatile("s_waitcnt vmcnt(0)" ::: "memory");
    __builtin_amdgcn_s_barrier();

    for (int t = 0; t < 16; ++t) {
        // stage this phase's V (both streams) + next phase's K (both streams)
        stageV(VA, t);
        stageV(VB, t + 16);
        if (t < 15) {
            stageK(KA[(t + 1) & 1], t + 1);
            stageK(KB[(t + 1) & 1], t + 17);
        }
        // QK^T: two interleaved independent 8-MFMA chains
        floatx16 sA, sB;
#pragma unroll
        for (int r = 0; r < 16; ++r) { sA[r] = -SHIFT; sB[r] = -SHIFT; }
        __builtin_amdgcn_s_setprio(1);
#pragma unroll
        for (int m = 0; m < 8; ++m) {
            int slot = l31 * 16 + ((m * 2 + hi) ^ (l31 & 15));
            short8 kfa = *(const short8*)(&KA[t & 1][slot * 8]);
            short8 kfb = *(const short8*)(&KB[t & 1][slot * 8]);
            sA = __builtin_amdgcn_mfma_f32_32x32x16_bf16(kfa, qf[m], sA, 0, 0, 0);
            sB = __builtin_amdgcn_mfma_f32_32x32x16_bf16(kfb, qf[m], sB, 0, 0, 0);
        }
        __builtin_amdgcn_s_setprio(0);
        // softmax, stream A then stream B (register-peak control)
        short8 pA0, pA1, pB0, pB1;
        softmax32(sA, pA0, pA1);
        softmax32(sB, pB0, pB1);
        // V (and next-K) landed + visible to all waves
        __syncthreads();
        // PV: 4 independent accO chains, 4 A-fragments each
        __builtin_amdgcn_s_setprio(1);
#pragma unroll
        for (int ntd = 0; ntd < 4; ++ntd) {
            int s0 = ((ntd * 2 + 0) * 2 + hi) * 32 + l31;
            int s1 = ((ntd * 2 + 1) * 2 + hi) * 32 + l31;
            short8 vA0 = *(const short8*)(&VA[s0 * 8]);
            short8 vA1 = *(const short8*)(&VA[s1 * 8]);
            short8 vB0 = *(const short8*)(&VB[s0 * 8]);
            short8 vB1 = *(const short8*)(&VB[s1 * 8]);
            accO[ntd] = __builtin_amdgcn_mfma_f32_32x32x16_bf16(pA0, vA0, accO[ntd], 0, 0, 0);
            accO[ntd] = __builtin_amdgcn_mfma_f32_32x32x16_bf16(pA1, vA1, accO[ntd], 0, 0, 0);
            accO[ntd] = __builtin_amdgcn_mfma_f32_32x32x16_bf16(pB0, vB0, accO[ntd], 0, 0, 0);
            accO[ntd] = __builtin_amdgcn_mfma_f32_32x32x16_bf16(pB1, vB1, accO[ntd], 0, 0, 0);
        }
        __builtin_amdgcn_s_setprio(0);
        __syncthreads();   // VA/VB + K[t&1] free for next phase's staging
    }

    // epilogue: psum covers half the keys; partner (lane^32) has the rest
    float s = psum + __shfl_xor(psum, 32);
    float rinv = 1.0f / s;  // valid for q = l31
    float ri[16];
#pragma unroll
    for (int r = 0; r < 16; ++r) {
        int row = (r & 3) + 8 * (r >> 2) + 4 * hi;
        ri[r] = __shfl(rinv, row);
    }
#pragma unroll
    for (int ntd = 0; ntd < 4; ++ntd)
#pragma unroll
        for (int r = 0; r < 16; ++r) {
            int row = (r & 3) + 8 * (r >> 2) + 4 * hi;
            O[(q0 + row) * HID + h * HD + ntd * 32 + l31] = accO[ntd][r] * ri[r];
        }
}

extern "C" void kernel_launch(void* const* d_in, const int* in_sizes, int n_in,
                              void* d_out, int out_size, void* d_ws, size_t ws_size,
                              hipStream_t stream) {
    const float* Q      = (const float*)d_in[0];
    const float* latent = (const float*)d_in[1];
    const float* freqs  = (const float*)d_in[2];
    const float* Wk     = (const float*)d_in[3];
    const float* Wv     = (const float*)d_in[4];
    const float* rmsw   = (const float*)d_in[5];
    float* out = (float*)d_out;
    char* ws = (char*)d_ws;

    // ws layout (62,914,560 bytes; Wv reuses Wk's slot — stream order serializes)
    unsigned short* latent_bf = (unsigned short*)(ws);               //  6,291,456
    unsigned short* Wbf       = (unsigned short*)(ws + 6291456);     // 18,874,368 (Wk, then Wv)
    float*          raw0      = (float*)(ws + 25165824);             // 12,582,912 split-K partial 0
    float*          raw1      = (float*)(ws + 37748736);             // 12,582,912 split-K partial 1
    unsigned short* Kbf       = (unsigned short*)(ws + 50331648);    //  6,291,456
    unsigned short* Vfrag     = (unsigned short*)(ws + 56623104);    //  6,291,456

    f32_to_bf16<<<2048, 256, 0, stream>>>(latent, latent_bf, (LK * HID) / 4);
    f32_to_bf16<<<2048, 256, 0, stream>>>(Wk, Wbf, (HID * HID) / 4);

    gemm_proj<<<dim3(16, 24, 2), 256, 0, stream>>>(latent_bf, Wbf, raw0, LK, HID, HID);
    rmsnorm_rope<<<(LK * NH) / 2, 256, 0, stream>>>(raw0, raw1, freqs, rmsw, Kbf);

    f32_to_bf16<<<2048, 256, 0, stream>>>(Wv, Wbf, (HID * HID) / 4);
    gemm_proj<<<dim3(16, 24, 2), 256, 0, stream>>>(latent_bf, Wbf, raw0, LK, HID, HID);
    transpose_v<<<dim3(HID / 64, LK / 32), 256, 0, stream>>>(raw0, raw1, Vfrag);

    attn<<<dim3(LQ / 128, NH), 256, 0, stream>>>(Q, Kbf, Vfrag, out);
}